// Round 4
// baseline (421.362 us; speedup 1.0000x reference)
//
#include <hip/hip_runtime.h>
#include <math.h>

#define BB 1024
#define CC 50000
#define DD 256
#define LRATE 0.5f

// ------------------------------------------------------------------
// K1: 2048 blocks. Blocks [0,1024): scan one-hot row b -> labels[b],
// compute dist = x - center[lab] (input center! no dependency on the
// copy), stash dist in ws, loss_norm[b]. Blocks [1024,2048): grid-
// stride float4 copy center -> out_center. No cross-block hazards.
#define CHUNK_ITERS 4                   // 4*256 uint4 = 4096 cols/chunk
__global__ void k_scan_copy(const unsigned int* __restrict__ y,
                            const float* __restrict__ x,
                            const float* __restrict__ center,
                            float4* __restrict__ out_center,
                            int* __restrict__ labels,
                            float* __restrict__ dist_ws,
                            float* __restrict__ loss_norm) {
    int blk = blockIdx.x;
    if (blk >= BB) {                    // ---- copy blocks ----
        int cb = blk - BB;
        const float4* src = (const float4*)center;
        const int n4 = CC * DD / 4;     // 3,200,000
        for (int i = cb * 256 + threadIdx.x; i < n4; i += BB * 256)
            out_center[i] = src[i];
        return;
    }
    // ---- scan blocks ----
    int b = blk;
    const uint4* row = (const uint4*)(y + (size_t)b * CC);
    __shared__ int s_lab;
    __shared__ float s_part[4];
    if (threadIdx.x == 0) s_lab = -1;
    __syncthreads();

    const int C4 = CC / 4;              // 12500
    for (int base = 0; base < C4; base += 256 * CHUNK_ITERS) {
        #pragma unroll
        for (int j = 0; j < CHUNK_ITERS; ++j) {
            int i = base + j * 256 + threadIdx.x;
            if (i < C4) {
                uint4 v = row[i];       // 0.0f bits == 0; 1.0f bits != 0
                if (v.x | v.y | v.z | v.w)
                    s_lab = 4 * i + (v.x ? 0 : (v.y ? 1 : (v.z ? 2 : 3)));
            }
        }
        __syncthreads();
        int found = s_lab;
        __syncthreads();
        if (found >= 0) break;          // block-uniform
    }

    int lab = s_lab;
    if (lab < 0) lab = 0;
    int d = threadIdx.x;                // DD == 256 == blockDim.x
    float dist = x[(size_t)b * DD + d] - center[(size_t)lab * DD + d];
    dist_ws[(size_t)b * DD + d] = dist;
    if (threadIdx.x == 0) labels[b] = lab;

    float sq = dist * dist;
    #pragma unroll
    for (int off = 32; off > 0; off >>= 1)
        sq += __shfl_down(sq, off, 64);
    if ((threadIdx.x & 63) == 0) s_part[threadIdx.x >> 6] = sq;
    __syncthreads();
    if (threadIdx.x == 0)
        loss_norm[b] = sqrtf(s_part[0] + s_part[1] + s_part[2] + s_part[3]);
}

// ------------------------------------------------------------------
// K2: loss write + center scatter. Each block serves a 1024-column
// tile x 16 rows. Counts come from an LDS histogram of labels[] (4 KB,
// L2-hit) — no counts buffer, no zero-pass, no atomics in HBM.
// Additionally, flat-id blocks < 1024 scatter LR*dist into out_center.
#define ROWS_PER_BLK 16
__global__ void k_loss_scatter(const float* __restrict__ loss_norm,
                               const int* __restrict__ labels,
                               const float* __restrict__ dist_ws,
                               float* __restrict__ out_loss,
                               float* __restrict__ out_center) {
    __shared__ int histo[1024];
    const int tid = threadIdx.x;
    const int c0 = blockIdx.x * 1024;           // first column of tile
    #pragma unroll
    for (int j = tid; j < 1024; j += 256) histo[j] = 0;
    __syncthreads();
    {   // 1024 labels as 256 int4 -> 1 per thread
        int4 lb = ((const int4*)labels)[tid];
        int l;
        l = lb.x - c0; if ((unsigned)l < 1024u) atomicAdd(&histo[l], 1);
        l = lb.y - c0; if ((unsigned)l < 1024u) atomicAdd(&histo[l], 1);
        l = lb.z - c0; if ((unsigned)l < 1024u) atomicAdd(&histo[l], 1);
        l = lb.w - c0; if ((unsigned)l < 1024u) atomicAdd(&histo[l], 1);
    }
    __syncthreads();

    const int C4 = CC / 4;                      // 12500
    int c4 = blockIdx.x * 256 + tid;
    if (c4 < C4) {
        float4 inv;
        inv.x = 1.0f / ((float)histo[4 * tid + 0] + 1.0f);
        inv.y = 1.0f / ((float)histo[4 * tid + 1] + 1.0f);
        inv.z = 1.0f / ((float)histo[4 * tid + 2] + 1.0f);
        inv.w = 1.0f / ((float)histo[4 * tid + 3] + 1.0f);
        int b0 = blockIdx.y * ROWS_PER_BLK;
        #pragma unroll
        for (int r = 0; r < ROWS_PER_BLK; ++r) {
            int b = b0 + r;
            float ln = loss_norm[b];
            float4 o;
            o.x = ln * inv.x; o.y = ln * inv.y; o.z = ln * inv.z; o.w = ln * inv.w;
            ((float4*)(out_loss + (size_t)b * CC))[c4] = o;
        }
    }

    // ---- scatter duty: first 1024 flat blocks, one sample each ----
    int fid = blockIdx.y * gridDim.x + blockIdx.x;
    if (fid < BB) {
        int lab = labels[fid];
        float dv = dist_ws[(size_t)fid * DD + tid];
        atomicAdd(&out_center[(size_t)lab * DD + tid], LRATE * dv);
    }
}

// ------------------------------------------------------------------
extern "C" void kernel_launch(void* const* d_in, const int* in_sizes, int n_in,
                              void* d_out, int out_size, void* d_ws, size_t ws_size,
                              hipStream_t stream) {
    const float* x        = (const float*)d_in[0];          // [B, D]
    const unsigned int* y = (const unsigned int*)d_in[1];   // [B, C] one-hot bits
    const float* center   = (const float*)d_in[2];          // [C, D]

    float* out_loss   = (float*)d_out;                      // [B, C]
    float* out_center = (float*)d_out + (size_t)BB * CC;    // [C, D]

    // ws layout: labels (4 KB) | dist (1 MB) | loss_norm (4 KB)
    int*   labels    = (int*)d_ws;
    float* dist_ws   = (float*)((char*)d_ws + 4096);
    float* loss_norm = (float*)((char*)d_ws + 4096 + (size_t)BB * DD * 4);

    k_scan_copy<<<2 * BB, DD, 0, stream>>>(
        y, x, center, (float4*)out_center, labels, dist_ws, loss_norm);

    dim3 lgrid((CC / 4 + 255) / 256, BB / ROWS_PER_BLK);    // (49, 64)
    k_loss_scatter<<<lgrid, 256, 0, stream>>>(
        loss_norm, labels, dist_ws, out_loss, out_center);
}